// Round 7
// baseline (473.220 us; speedup 1.0000x reference)
//
#include <hip/hip_runtime.h>
#include <cstdint>
#include <cstddef>

// ---------------------------------------------------------------------------
// GCN 2-layer encoder.  Pipeline per launch (12 dispatches):
//   1. bin_count: 782-bin histogram of dst>>7
//   2. bin_scan:  binStart/binCursor (fine) + superCursor (dst>>11, 49 bins)
//   3. super_fill: partition edges into super-bins (1 tile/block, reg-prefetch,
//      wave-parallel scan)
//   4. fine_fill:  scatter each super-segment into its 16 fine bins
//   5. node_count_dis: per-fine-bin LDS degree count -> count[], dis[]
//   6. bin_csr: per-bin LDS scan -> rowptr + col scatter
//   7. wsplit: W1/W2 -> transposed split-bf16 planes [2][64][K] (hi, lo)
//   8. gemm1_mfma -> h1 bf16: per-wave LDS-DMA ring (x via global_load_lds,
//      zero VGPR cost) + IN-ITERATION weight loads (L2-resident 64 KB table;
//      latency hides under ds_read; compiler MFMA-wait = vmcnt(4), never
//      drains the DMA queue).  No weight double-buffer -> no spill (r5 lesson:
//      VGPR 84 proved w[2][8] spilled to scratch).
//   9. agg1 -> out1 (bf16, relu); 4 nodes/wave, batched prologue
//  10. gemm2_mfma -> h2 bf16 (A exact bf16, 2-term)
//  11. agg2 -> d_out (fp32)
// MFMA orientation: D[n][m] = Wt[n][k] * x[m][k]^T so each lane holds 4
// consecutive output cols of one node -> packs straight into uint2 bf16.
// ---------------------------------------------------------------------------

#define BIN_SHIFT 7
#define BIN_NODES 128
#define MAX_BINS 1024
#define SUP_SHIFT 11
#define FINE_PER_SUP 16
#define NSUP_MAX 64
#define SCAP 56  // per-super staging capacity per 2048-edge tile (mean 42)
#define SRC_BITS 17
#define SRC_MASK ((1 << SRC_BITS) - 1)

typedef unsigned short ushort_t;

typedef __attribute__((ext_vector_type(8))) short bf16x8;  // 8 bf16 (4 VGPRs)
typedef __attribute__((ext_vector_type(4))) float f32x4;   // MFMA accumulator

union FragB {
  uint4 u;
  bf16x8 b;
};

__device__ __forceinline__ float4 bfq2f4(uint2 p) {  // 4 packed bf16 -> fp32 (exact)
  float4 r;
  r.x = __uint_as_float(p.x << 16);
  r.y = __uint_as_float(p.x & 0xFFFF0000u);
  r.z = __uint_as_float(p.y << 16);
  r.w = __uint_as_float(p.y & 0xFFFF0000u);
  return r;
}
__device__ __forceinline__ unsigned f2bf(float f) {  // fp32 -> bf16 bits, RNE
  unsigned u = __float_as_uint(f);
  return (u + 0x7FFFu + ((u >> 16) & 1u)) >> 16;
}
__device__ __forceinline__ uint2 f42bfq(float4 f) {
  uint2 r;
  r.x = f2bf(f.x) | (f2bf(f.y) << 16);
  r.y = f2bf(f.z) | (f2bf(f.w) << 16);
  return r;
}

__global__ void zero_int(int* __restrict__ p, int n) {
  int i = blockIdx.x * blockDim.x + threadIdx.x;
  if (i < n) p[i] = 0;
}

// --- pass 1: fine histogram -------------------------------------------------
__global__ __launch_bounds__(256) void bin_count(const int* __restrict__ dst, int E, int nbins,
                                                 int* __restrict__ binCnt) {
  __shared__ int h[MAX_BINS];
  for (int i = threadIdx.x; i < nbins; i += 256) h[i] = 0;
  __syncthreads();
  int stride = gridDim.x * 256;
  for (int e = blockIdx.x * 256 + threadIdx.x; e < E; e += stride)
    atomicAdd(&h[dst[e] >> BIN_SHIFT], 1);
  __syncthreads();
  for (int i = threadIdx.x; i < nbins; i += 256)
    if (h[i]) atomicAdd(&binCnt[i], h[i]);
}

// --- pass 2: scan fine bins; derive super cursors ---------------------------
__global__ __launch_bounds__(256) void bin_scan(const int* __restrict__ binCnt, int nbins, int E,
                                                int* __restrict__ binStart,
                                                int* __restrict__ binCursor,
                                                int* __restrict__ supCursor) {
  __shared__ int s[256];
  int t = threadIdx.x;
  int c[4];
  int sum = 0;
#pragma unroll
  for (int i = 0; i < 4; i++) {
    int idx = t * 4 + i;
    c[i] = (idx < nbins) ? binCnt[idx] : 0;
    sum += c[i];
  }
  int v = sum;
  s[t] = v;
  __syncthreads();
  for (int d = 1; d < 256; d <<= 1) {
    int add = (t >= d) ? s[t - d] : 0;
    __syncthreads();
    s[t] += add;
    __syncthreads();
  }
  int run = s[t] - v;  // exclusive prefix
#pragma unroll
  for (int i = 0; i < 4; i++) {
    int idx = t * 4 + i;
    if (idx < nbins) {
      binStart[idx] = run;
      binCursor[idx] = run;
      if ((idx & (FINE_PER_SUP - 1)) == 0) supCursor[idx >> 4] = run;  // super segment start
      run += c[i];
    }
  }
  if (t == 0) binStart[nbins] = E;
}

// --- pass 3: partition into super-bins, one 2048-edge tile per block --------
__global__ __launch_bounds__(256) void super_fill(const int* __restrict__ src,
                                                  const int* __restrict__ dst, int E, int nsup,
                                                  int* __restrict__ supCursor,
                                                  unsigned* __restrict__ supbuf) {
  __shared__ unsigned stage[NSUP_MAX * SCAP];
  __shared__ int lcnt[NSUP_MAX], lbase[NSUP_MAX], lscan[NSUP_MAX + 1];
  const int tid = threadIdx.x;
  const int t0 = blockIdx.x * 2048;
  const int t1 = min(E, t0 + 2048);

  int dv[8], sv[8];
#pragma unroll
  for (int i = 0; i < 8; i++) {
    int e = t0 + i * 256 + tid;
    if (e < t1) {
      dv[i] = dst[e];
      sv[i] = src[e];
    }
  }
  if (tid < nsup) lcnt[tid] = 0;
  __syncthreads();
#pragma unroll
  for (int i = 0; i < 8; i++) {
    int e = t0 + i * 256 + tid;
    if (e < t1) {
      int d = dv[i];
      int sb = d >> SUP_SHIFT;
      unsigned v = ((unsigned)(d & ((1 << SUP_SHIFT) - 1)) << SRC_BITS) | (unsigned)sv[i];
      int idx = atomicAdd(&lcnt[sb], 1);
      if (idx < SCAP)
        stage[sb * SCAP + idx] = v;
      else {  // rare overflow: direct write
        int g = atomicAdd(&supCursor[sb], 1);
        supbuf[g] = v;
      }
    }
  }
  __syncthreads();
  if (tid < nsup) {
    int c = min(lcnt[tid], SCAP);
    lcnt[tid] = c;
    lbase[tid] = c ? atomicAdd(&supCursor[tid], c) : 0;
  }
  __syncthreads();
  if (tid < 64) {  // wave-0 inclusive scan over 64 bins
    int vv = (tid < nsup) ? lcnt[tid] : 0;
    int ss = vv;
#pragma unroll
    for (int d = 1; d < 64; d <<= 1) {
      int u = __shfl_up(ss, d);
      if (tid >= d) ss += u;
    }
    lscan[tid + 1] = ss;
    if (tid == 0) lscan[0] = 0;
  }
  __syncthreads();
  int total = lscan[nsup];
  for (int j = tid; j < total; j += 256) {
    int lo = 0, hi = nsup;  // binary search: lscan[lo] <= j < lscan[lo+1]
    while (hi - lo > 1) {
      int mid = (lo + hi) >> 1;
      if (lscan[mid] <= j)
        lo = mid;
      else
        hi = mid;
    }
    int off = j - lscan[lo];
    supbuf[lbase[lo] + off] = stage[lo * SCAP + off];
  }
}

// --- pass 4: scatter super-segment into its 16 fine bins (L2 window) --------
__global__ __launch_bounds__(256) void fine_fill(const unsigned* __restrict__ supbuf,
                                                 const int* __restrict__ binStart, int nbins,
                                                 int* __restrict__ binCursor,
                                                 unsigned* __restrict__ binbuf) {
  __shared__ int lcnt[FINE_PER_SUP], lbase[FINE_PER_SUP];
  int sb = blockIdx.x >> 3, p = blockIdx.x & 7;
  int seg0 = binStart[sb << 4];
  int seg1 = binStart[min((sb + 1) << 4, nbins)];
  int part = (seg1 - seg0 + 7) >> 3;
  int c0 = seg0 + p * part;
  int c1 = min(seg1, c0 + part);
  if (threadIdx.x < FINE_PER_SUP) lcnt[threadIdx.x] = 0;
  __syncthreads();
  for (int i = c0 + threadIdx.x; i < c1; i += 256) atomicAdd(&lcnt[supbuf[i] >> 24], 1);
  __syncthreads();
  if (threadIdx.x < FINE_PER_SUP) {
    int c = lcnt[threadIdx.x];
    lbase[threadIdx.x] = c ? atomicAdd(&binCursor[(sb << 4) + threadIdx.x], c) : 0;
    lcnt[threadIdx.x] = 0;
  }
  __syncthreads();
  for (int i = c0 + threadIdx.x; i < c1; i += 256) {
    unsigned v = supbuf[i];
    unsigned dls = v >> SRC_BITS;  // 11-bit dst-local-to-super
    int f = dls >> BIN_SHIFT;      // fine bin within super
    unsigned vf = ((dls & (BIN_NODES - 1)) << SRC_BITS) | (v & SRC_MASK);
    int idx = lbase[f] + atomicAdd(&lcnt[f], 1);
    binbuf[idx] = vf;
  }
}

// --- pass 5: per-bin node degree + dis --------------------------------------
__global__ __launch_bounds__(256) void node_count_dis(const unsigned* __restrict__ binbuf,
                                                      const int* __restrict__ binStart, int N,
                                                      int* __restrict__ count,
                                                      float* __restrict__ dis) {
  __shared__ int cnt[BIN_NODES];
  int b = blockIdx.x;
  int nodeBase = b << BIN_SHIFT;
  if (threadIdx.x < BIN_NODES) cnt[threadIdx.x] = 0;
  __syncthreads();
  int s0 = binStart[b], s1 = binStart[b + 1];
  for (int i = s0 + threadIdx.x; i < s1; i += 256) atomicAdd(&cnt[binbuf[i] >> SRC_BITS], 1);
  __syncthreads();
  if (threadIdx.x < BIN_NODES) {
    int node = nodeBase + threadIdx.x;
    if (node < N) {
      int c = cnt[threadIdx.x];
      count[node] = c;
      dis[node] = rsqrtf((float)(c + 1));  // +1 self loop
    }
  }
}

// --- pass 6: fused per-bin scan + CSR col scatter ---------------------------
__global__ __launch_bounds__(256) void bin_csr(const unsigned* __restrict__ binbuf,
                                               const int* __restrict__ binStart,
                                               const int* __restrict__ count, int N, int E,
                                               int* __restrict__ rowptr, int* __restrict__ col) {
  __shared__ int cur[BIN_NODES];
  __shared__ int pref[BIN_NODES];
  int b = blockIdx.x, t = threadIdx.x;
  int nodeBase = b << BIN_SHIFT;
  int c = 0;
  if (t < BIN_NODES) {
    int node = nodeBase + t;
    c = (node < N) ? count[node] : 0;
    pref[t] = c;
  }
  __syncthreads();
  for (int d = 1; d < BIN_NODES; d <<= 1) {  // inclusive scan over 128
    int add = (t < BIN_NODES && t >= d) ? pref[t - d] : 0;
    __syncthreads();
    if (t < BIN_NODES) pref[t] += add;
    __syncthreads();
  }
  int s0 = binStart[b];
  if (t < BIN_NODES) {
    int node = nodeBase + t;
    if (node < N) {
      int ex = s0 + pref[t] - c;  // exclusive prefix + segment base
      rowptr[node] = ex;
      cur[t] = ex;
    }
  }
  if (b == 0 && t == 255) rowptr[N] = E;
  __syncthreads();
  int s1 = binStart[b + 1];
  for (int i = s0 + t; i < s1; i += 256) {
    unsigned v = binbuf[i];
    int slot = atomicAdd(&cur[v >> SRC_BITS], 1);
    col[slot] = v & SRC_MASK;
  }
}

// --- pass 7: split W1/W2 into transposed bf16 hi/lo planes ------------------
__global__ __launch_bounds__(256) void wsplit(const float* __restrict__ W1,
                                              const float* __restrict__ W2,
                                              ushort_t* __restrict__ wt1,
                                              ushort_t* __restrict__ wt2) {
  int i = blockIdx.x * 256 + threadIdx.x;
  const float* W;
  ushort_t* wt;
  int K, idx;
  if (i < 256 * 64) {
    W = W1; wt = wt1; K = 256; idx = i;
  } else if (i < 256 * 64 + 64 * 64) {
    W = W2; wt = wt2; K = 64; idx = i - 256 * 64;
  } else
    return;
  int n = idx & 63, k = idx >> 6;
  float f = W[k * 64 + n];  // W is [K][64] row-major
  unsigned u = __float_as_uint(f);
  unsigned hb = u & 0xFFFF0000u;
  float lo = f - __uint_as_float(hb);
  wt[(size_t)n * K + k] = (ushort_t)(u >> 16);
  wt[(size_t)64 * K + (size_t)n * K + k] = (ushort_t)(__float_as_uint(lo) >> 16);
}

// split 8 packed fp32 (as 2 uint4) into bf16 hi (truncate) + lo (trunc resid)
__device__ __forceinline__ void split8u(uint4 a, uint4 b, uint4& xh, uint4& xl) {
  unsigned ua[8] = {a.x, a.y, a.z, a.w, b.x, b.y, b.z, b.w};
  unsigned hw[4], lw[4];
#pragma unroll
  for (int p = 0; p < 4; p++) {
    unsigned u0 = ua[2 * p], u1 = ua[2 * p + 1];
    unsigned h0 = u0 & 0xFFFF0000u, h1 = u1 & 0xFFFF0000u;
    float l0 = __uint_as_float(u0) - __uint_as_float(h0);
    float l1 = __uint_as_float(u1) - __uint_as_float(h1);
    hw[p] = (u0 >> 16) | h1;
    lw[p] = (__float_as_uint(l0) >> 16) | (__float_as_uint(l1) & 0xFFFF0000u);
  }
  xh = make_uint4(hw[0], hw[1], hw[2], hw[3]);
  xl = make_uint4(lw[0], lw[1], lw[2], lw[3]);
}

// --- gemm1: Cbf16[M][64] = x[M][256] @ W1, per-wave LDS-DMA ring ------------
// Each wave owns 32 nodes; per 32-wide k-tile it DMAs its 32 rows (4 KB) into
// its slice of a 3-buffer LDS ring via global_load_lds (4 calls x 1 KB) --
// zero VGPR cost.  Weights loaded IN-ITERATION (L2-resident 64 KB table);
// their L2 latency hides under the ds_reads, and the compiler's MFMA wait is
// vmcnt(4) (only the just-issued stage ops are younger) -- the DMA queue is
// never drained.  Wait ledger: entering iter j, queue = [st(j):4, st(j+1):4];
// explicit vmcnt(4) drains exactly st(j) (j=7: vmcnt(0)).  No __syncthreads.
__global__ __launch_bounds__(256, 3) void gemm1_mfma(const float* __restrict__ A,
                                                     const ushort_t* __restrict__ Wt,
                                                     uint2* __restrict__ Cb, int M) {
  constexpr int K = 256;
  __shared__ uint4 xtile[3][4][256];  // [ring buf][wave][slot] = 48 KB
  const int lane = threadIdx.x & 63;
  const int wv = threadIdx.x >> 6;
  const int l15 = lane & 15;
  const int lq = lane >> 4;
  const int m0 = blockIdx.x * 128 + wv * 32;

  const ushort_t* __restrict__ Wlo = Wt + (size_t)64 * K;

  f32x4 acc[2][4];
#pragma unroll
  for (int a = 0; a < 2; a++)
#pragma unroll
    for (int b = 0; b < 4; b++) acc[a][b] = (f32x4){0.f, 0.f, 0.f, 0.f};

  // stage tile kt into ring buffer buf (this wave's 32 rows, 4 KB, 4 DMA calls)
  auto stage_tile = [&](int kt, int buf) {
#pragma unroll
    for (int c = 0; c < 4; c++) {
      int s = c * 64 + lane;
      int r = s >> 3;                 // row 0..31 within wave block
      int c4 = (s & 7) ^ (r & 7);     // swizzled float4-column
      int nd = m0 + r;
      if (nd >= M) nd = M - 1;
      const float* gp = A + (size_t)nd * K + kt * 32 + c4 * 4;
      __builtin_amdgcn_global_load_lds(
          (const __attribute__((address_space(1))) void*)gp,
          (__attribute__((address_space(3))) void*)&xtile[buf][wv][c * 64], 16, 0, 0);
    }
  };

  // prologue: st(0), st(1)
  stage_tile(0, 0);
  stage_tile(1, 1);
  __builtin_amdgcn_sched_barrier(0);

#pragma unroll
  for (int j = 0; j < 8; j++) {
    // a. ensure tile j staged (drain exactly st(j); keep st(j+1))
    if (j < 7)
      asm volatile("s_waitcnt vmcnt(4)" ::: "memory");
    else
      asm volatile("s_waitcnt vmcnt(0)" ::: "memory");
    __builtin_amdgcn_sched_barrier(0);
    // b. issue this iteration's weight loads (independent of LDS; latency
    //    hides under the ds_reads below)
    FragB w[8];
    {
      const int kb = j * 32 + lq * 8;
#pragma unroll
      for (int nt = 0; nt < 4; nt++) {
        w[nt].u = *(const uint4*)(Wt + (size_t)(nt * 16 + l15) * K + kb);
        w[4 + nt].u = *(const uint4*)(Wlo + (size_t)(nt * 16 + l15) * K + kb);
      }
    }
    // c. ds_read tile j fragments (swizzled)
    uint4 xa[2][2];
#pragma unroll
    for (int mt = 0; mt < 2; mt++) {
      int mr = mt * 16 + l15;
#pragma unroll
      for (int hh = 0; hh < 2; hh++) {
        int c4 = (lq * 2 + hh) ^ (mr & 7);
        xa[mt][hh] = *(const uint4*)&xtile[j % 3][wv][mr * 8 + c4];
      }
    }
    __builtin_amdgcn_sched_barrier(0);
    // d. issue stage for tile j+2
    if (j + 2 < 8) stage_tile(j + 2, (j + 2) % 3);
    __builtin_amdgcn_sched_barrier(0);
    // e. split + MFMA (compiler weight-wait = vmcnt(4), keeps st(j+2) alive)
    FragB xh0, xl0, xh1, xl1;
    split8u(xa[0][0], xa[0][1], xh0.u, xl0.u);
    split8u(xa[1][0], xa[1][1], xh1.u, xl1.u);
#pragma unroll
    for (int nt = 0; nt < 4; nt++) {
      acc[0][nt] = __builtin_amdgcn_mfma_f32_16x16x32_bf16(w[nt].b, xh0.b, acc[0][nt], 0, 0, 0);
      acc[0][nt] = __builtin_amdgcn_mfma_f32_16x16x32_bf16(w[nt].b, xl0.b, acc[0][nt], 0, 0, 0);
      acc[1][nt] = __builtin_amdgcn_mfma_f32_16x16x32_bf16(w[nt].b, xh1.b, acc[1][nt], 0, 0, 0);
      acc[1][nt] = __builtin_amdgcn_mfma_f32_16x16x32_bf16(w[nt].b, xl1.b, acc[1][nt], 0, 0, 0);
    }
#pragma unroll
    for (int nt = 0; nt < 4; nt++) {
      acc[0][nt] = __builtin_amdgcn_mfma_f32_16x16x32_bf16(w[4 + nt].b, xh0.b, acc[0][nt], 0, 0, 0);
      acc[1][nt] = __builtin_amdgcn_mfma_f32_16x16x32_bf16(w[4 + nt].b, xh1.b, acc[1][nt], 0, 0, 0);
    }
  }

#pragma unroll
  for (int mt = 0; mt < 2; mt++) {
    int node = m0 + mt * 16 + l15;
    if (node < M) {
      uint2* cp = Cb + (size_t)node * 16 + lq;
#pragma unroll
      for (int nt = 0; nt < 4; nt++) {
        float4 o = make_float4(acc[mt][nt][0], acc[mt][nt][1], acc[mt][nt][2], acc[mt][nt][3]);
        cp[nt * 4] = f42bfq(o);  // cols nt*16 + lq*4 .. +3
      }
    }
  }
}

// --- gemm2: Cbf16[M][64] = out1[M][64] @ W2 (A exact bf16, 2-term) ----------
__global__ __launch_bounds__(256, 3) void gemm2_mfma(const ushort_t* __restrict__ Av,
                                                     const ushort_t* __restrict__ Wt,
                                                     uint2* __restrict__ Cb, int M) {
  constexpr int K = 64;
  constexpr int NT = K / 32;  // 2
  const int lane = threadIdx.x & 63;
  const int wv = threadIdx.x >> 6;
  const int l15 = lane & 15;
  const int lq = lane >> 4;
  const int m0 = blockIdx.x * 128 + wv * 32;

  const ushort_t* __restrict__ Wlo = Wt + (size_t)64 * K;

  f32x4 acc[2][4];
#pragma unroll
  for (int a = 0; a < 2; a++)
#pragma unroll
    for (int b = 0; b < 4; b++) acc[a][b] = (f32x4){0.f, 0.f, 0.f, 0.f};

  int node[2], ncl[2];
#pragma unroll
  for (int mt = 0; mt < 2; mt++) {
    node[mt] = m0 + mt * 16 + l15;
    ncl[mt] = node[mt] < M ? node[mt] : (M - 1);
  }

  FragB xa[NT][2], wh[NT][4], wl[NT][4];
#pragma unroll
  for (int t = 0; t < NT; t++)
#pragma unroll
    for (int mt = 0; mt < 2; mt++)
      xa[t][mt].u = *(const uint4*)(Av + (size_t)ncl[mt] * K + t * 32 + lq * 8);
#pragma unroll
  for (int t = 0; t < NT; t++)
#pragma unroll
    for (int nt = 0; nt < 4; nt++) {
      wh[t][nt].u = *(const uint4*)(Wt + (size_t)(nt * 16 + l15) * K + t * 32 + lq * 8);
      wl[t][nt].u = *(const uint4*)(Wlo + (size_t)(nt * 16 + l15) * K + t * 32 + lq * 8);
    }
#pragma unroll
  for (int t = 0; t < NT; t++)
#pragma unroll
    for (int mt = 0; mt < 2; mt++)
#pragma unroll
      for (int nt = 0; nt < 4; nt++) {
        acc[mt][nt] =
            __builtin_amdgcn_mfma_f32_16x16x32_bf16(wh[t][nt].b, xa[t][mt].b, acc[mt][nt], 0, 0, 0);
        acc[mt][nt] =
            __builtin_amdgcn_mfma_f32_16x16x32_bf16(wl[t][nt].b, xa[t][mt].b, acc[mt][nt], 0, 0, 0);
      }

#pragma unroll
  for (int mt = 0; mt < 2; mt++) {
    if (node[mt] < M) {
      uint2* cp = Cb + (size_t)node[mt] * 16 + lq;
#pragma unroll
      for (int nt = 0; nt < 4; nt++) {
        float4 o = make_float4(acc[mt][nt][0], acc[mt][nt][1], acc[mt][nt][2], acc[mt][nt][3]);
        cp[nt * 4] = f42bfq(o);
      }
    }
  }
}

// --- aggregation: wave per 4 nodes, batched prologue, bf16 gather -----------
// w_edge = dis[src]; final sum scaled by di = dis[dst] once:
//   out = di * ( sum_j dis[src_j]*h_j + di*h_self ) + bias
// All 5 rowptr + 4 dis loads issue in parallel at wave start; one latency
// exposure amortized over 4 nodes' work (r5: 1-node waves were >50% prologue).
template <bool OUTBF>
__global__ __launch_bounds__(256) void agg_kernel(
    const uint2* __restrict__ h, const int* __restrict__ rowptr, const int* __restrict__ col,
    const float* __restrict__ dis, const float* __restrict__ bias, void* __restrict__ outv,
    int N, int relu) {
  int wq = (blockIdx.x * blockDim.x + threadIdx.x) >> 6;
  int n0 = wq * 4;
  if (n0 >= N) return;
  int lane = threadIdx.x & 63;
  int sub = lane & 15;
  int quarter = lane >> 4;

  int rp[5];
  float dd[4];
#pragma unroll
  for (int i = 0; i < 5; i++) rp[i] = rowptr[min(n0 + i, N)];
#pragma unroll
  for (int i = 0; i < 4; i++) dd[i] = (n0 + i < N) ? dis[n0 + i] : 0.f;
  float4 bv = ((const float4*)bias)[sub];

#pragma unroll
  for (int ni = 0; ni < 4; ni++) {
    int wid = n0 + ni;
    if (wid >= N) break;
    int start = rp[ni], end = rp[ni + 1];
    float di = dd[ni];

    float4 a0 = make_float4(0.f, 0.f, 0.f, 0.f), a1 = a0, a2 = a0, a3 = a0;
    {  // self-loop: di*h_self (quarter 0 only); final *di makes it di^2
      float4 self = bfq2f4(h[(size_t)wid * 16 + sub]);
      if (quarter == 0) {
        a0.x = di * self.x;
        a0.y = di * self.y;
        a0.z = di * self.z;
        a0.w = di * self.w;
      }
    }

    for (int base = start; base < end; base += 64) {
      int e = base + lane;
      int sj = 0;
      float wj = 0.f;
      if (e < end) {
        sj = col[e];
        wj = dis[sj];  // L2-resident 400 KB table
      }
      int cnt = end - base;
      if (cnt > 64) cnt = 64;
      int rounds = (cnt + 3) >> 2;
      int t = 0;
      for (; t + 4 <= rounds; t += 4) {
        int i0 = 4 * t + quarter;
        int s0 = __shfl(sj, i0), s1 = __shfl(sj, i0 + 4), s2 = __shfl(sj, i0 + 8),
            s3 = __shfl(sj, i0 + 12);
        float w0 = __shfl(wj, i0), w1 = __shfl(wj, i0 + 4), w2 = __shfl(wj, i0 + 8),
              w3 = __shfl(wj, i0 + 12);
        float4 g0 = bfq2f4(h[(size_t)s0 * 16 + sub]);
        float4 g1 = bfq2f4(h[(size_t)s1 * 16 + sub]);
        float4 g2 = bfq2f4(h[(size_t)s2 * 16 + sub]);
        float4 g3 = bfq2f4(h[(size_t)s3 * 16 + sub]);
        a0.x += w0 * g0.x; a0.y += w0 * g0.y; a0.z += w0 * g0.z; a0.w += w0 * g0.w;
        a1.x += w1 * g1.x; a1.y += w1 * g1.y; a1.z += w1 * g1.z; a1.w += w1 * g1.w;
        a2.x += w2 * g2.x; a2.y += w2 * g2.y; a2.z += w2 * g2.z; a2.w += w2 * g2.w;
        a3.x += w3 * g3.x; a3.y += w3 * g3.y; a3.z += w3 * g3.z; a3.w += w3 * g3.w;
      }
      for (; t < rounds; t++) {
        int i0 = 4 * t + quarter;  // tail quarters past cnt have wj==0
        int s0 = __shfl(sj, i0);
        float w0 = __shfl(wj, i0);
        float4 g0 = bfq2f4(h[(size_t)s0 * 16 + sub]);
        a0.x += w0 * g0.x; a0.y += w0 * g0.y; a0.z += w0 * g0.z; a0.w += w0 * g0.w;
      }
    }

    float sx = (a0.x + a1.x) + (a2.x + a3.x);
    float sy = (a0.y + a1.y) + (a2.y + a3.y);
    float sz = (a0.z + a1.z) + (a2.z + a3.z);
    float sw = (a0.w + a1.w) + (a2.w + a3.w);
    sx += __shfl_down(sx, 32); sy += __shfl_down(sy, 32);
    sz += __shfl_down(sz, 32); sw += __shfl_down(sw, 32);
    sx += __shfl_down(sx, 16); sy += __shfl_down(sy, 16);
    sz += __shfl_down(sz, 16); sw += __shfl_down(sw, 16);
    if (quarter == 0) {
      float4 o = make_float4(di * sx + bv.x, di * sy + bv.y, di * sz + bv.z, di * sw + bv.w);
      if (relu) {
        o.x = fmaxf(o.x, 0.f);
        o.y = fmaxf(o.y, 0.f);
        o.z = fmaxf(o.z, 0.f);
        o.w = fmaxf(o.w, 0.f);
      }
      if (OUTBF)
        ((uint2*)outv)[(size_t)wid * 16 + sub] = f42bfq(o);
      else
        ((float4*)outv)[(size_t)wid * 16 + sub] = o;
    }
  }
}

// ---------------------------------------------------------------------------
extern "C" void kernel_launch(void* const* d_in, const int* in_sizes, int n_in,
                              void* d_out, int out_size, void* d_ws, size_t ws_size,
                              hipStream_t stream) {
  const float* x = (const float*)d_in[0];
  const int* ei = (const int*)d_in[1];
  const float* W1 = (const float*)d_in[2];
  const float* b1 = (const float*)d_in[3];
  const float* W2 = (const float*)d_in[4];
  const float* b2 = (const float*)d_in[5];

  const int IN = 256;
  const int E = in_sizes[1] / 2;
  const int N = in_sizes[0] / IN;
  const int* src = ei;
  const int* dst = ei + E;
  const int nbins = (N + BIN_NODES - 1) >> BIN_SHIFT;
  const int nsup = (N + (1 << SUP_SHIFT) - 1) >> SUP_SHIFT;

  // workspace carve-up (256B aligned)
  char* ws = (char*)d_ws;
  size_t off = 0;
  auto alloc = [&](size_t bytes) -> void* {
    void* p = ws + off;
    off += (bytes + 255) & ~(size_t)255;
    return p;
  };
  int* count = (int*)alloc((size_t)N * 4);
  int* rowptr = (int*)alloc((size_t)(N + 1) * 4);
  float* dis = (float*)alloc((size_t)N * 4);
  int* binCnt = (int*)alloc(MAX_BINS * 4);
  int* binStart = (int*)alloc((MAX_BINS + 1) * 4);
  int* binCursor = (int*)alloc(MAX_BINS * 4);
  int* supCursor = (int*)alloc(NSUP_MAX * 4);
  int* col = (int*)alloc((size_t)E * 4);                // 12.8 MB; written by bin_csr
  unsigned* supbuf = (unsigned*)col;                    // alias: dead before col written
  uint2* out1 = (uint2*)alloc((size_t)N * 64 * 2);      // bf16 layer-1 activations
  size_t big = ((size_t)E * 4 > (size_t)N * 128) ? (size_t)E * 4 : (size_t)N * 128;
  unsigned* binbuf = (unsigned*)alloc(big);             // aliases h (dead before gemm1)
  uint2* h = (uint2*)binbuf;
  ushort_t* wt1 = (ushort_t*)alloc((size_t)2 * 64 * 256 * 2);  // 64 KB split W1
  ushort_t* wt2 = (ushort_t*)alloc((size_t)2 * 64 * 64 * 2);   // 16 KB split W2
  float* outf = (float*)d_out;

  zero_int<<<(nbins + 255) / 256, 256, 0, stream>>>(binCnt, nbins);
  bin_count<<<1024, 256, 0, stream>>>(dst, E, nbins, binCnt);
  bin_scan<<<1, 256, 0, stream>>>(binCnt, nbins, E, binStart, binCursor, supCursor);
  super_fill<<<(E + 2047) / 2048, 256, 0, stream>>>(src, dst, E, nsup, supCursor, supbuf);
  fine_fill<<<nsup * 8, 256, 0, stream>>>(supbuf, binStart, nbins, binCursor, binbuf);
  node_count_dis<<<nbins, 256, 0, stream>>>(binbuf, binStart, N, count, dis);
  bin_csr<<<nbins, 256, 0, stream>>>(binbuf, binStart, count, N, E, rowptr, col);
  wsplit<<<(256 * 64 + 64 * 64 + 255) / 256, 256, 0, stream>>>(W1, W2, wt1, wt2);

  gemm1_mfma<<<(N + 127) / 128, 256, 0, stream>>>(x, wt1, h, N);
  agg_kernel<true><<<(N + 15) / 16, 256, 0, stream>>>(h, rowptr, col, dis, b1, out1, N, 1);
  gemm2_mfma<<<(N + 127) / 128, 256, 0, stream>>>((const ushort_t*)out1, wt2, h, N);
  agg_kernel<false><<<(N + 15) / 16, 256, 0, stream>>>(h, rowptr, col, dis, b2, outf, N, 0);
}

// Round 8
// 461.267 us; speedup vs baseline: 1.0259x; 1.0259x over previous
//
#include <hip/hip_runtime.h>
#include <cstdint>
#include <cstddef>

// ---------------------------------------------------------------------------
// GCN 2-layer encoder.  Pipeline per launch (12 dispatches):
//   1. bin_count: 782-bin histogram of dst>>7
//   2. bin_scan:  binStart/binCursor (fine) + superCursor (dst>>11, 49 bins)
//   3. super_fill: partition edges into super-bins (1 tile/block, reg-prefetch,
//      wave-parallel scan)
//   4. fine_fill:  scatter each super-segment into its 16 fine bins
//   5. node_count_dis: per-fine-bin LDS degree count -> count[], dis[]
//   6. bin_csr: per-bin LDS scan -> rowptr + col scatter
//   7. wsplit: W1/W2 -> transposed split-bf16 planes [2][64][K] (hi, lo)
//   8. gemm1_mfma -> h1 bf16: per-wave LDS-DMA ring; weights issued BEFORE
//      the DMA wait so their L2 latency overlaps it (vmcnt ledger recounted:
//      12 steady / 8 tail).
//   9. agg1 -> out1 (bf16, relu); 1 node/wave + depth-4 rolling gather pipe
//  10. gemm2_mfma -> h2 bf16 (A exact bf16, 2-term)
//  11. agg2 -> d_out (fp32)
// MFMA orientation: D[n][m] = Wt[n][k] * x[m][k]^T so each lane holds 4
// consecutive output cols of one node -> packs straight into uint2 bf16.
// ---------------------------------------------------------------------------

#define BIN_SHIFT 7
#define BIN_NODES 128
#define MAX_BINS 1024
#define SUP_SHIFT 11
#define FINE_PER_SUP 16
#define NSUP_MAX 64
#define SCAP 56  // per-super staging capacity per 2048-edge tile (mean 42)
#define SRC_BITS 17
#define SRC_MASK ((1 << SRC_BITS) - 1)

typedef unsigned short ushort_t;

typedef __attribute__((ext_vector_type(8))) short bf16x8;  // 8 bf16 (4 VGPRs)
typedef __attribute__((ext_vector_type(4))) float f32x4;   // MFMA accumulator

union FragB {
  uint4 u;
  bf16x8 b;
};

__device__ __forceinline__ float4 bfq2f4(uint2 p) {  // 4 packed bf16 -> fp32 (exact)
  float4 r;
  r.x = __uint_as_float(p.x << 16);
  r.y = __uint_as_float(p.x & 0xFFFF0000u);
  r.z = __uint_as_float(p.y << 16);
  r.w = __uint_as_float(p.y & 0xFFFF0000u);
  return r;
}
__device__ __forceinline__ unsigned f2bf(float f) {  // fp32 -> bf16 bits, RNE
  unsigned u = __float_as_uint(f);
  return (u + 0x7FFFu + ((u >> 16) & 1u)) >> 16;
}
__device__ __forceinline__ uint2 f42bfq(float4 f) {
  uint2 r;
  r.x = f2bf(f.x) | (f2bf(f.y) << 16);
  r.y = f2bf(f.z) | (f2bf(f.w) << 16);
  return r;
}

__global__ void zero_int(int* __restrict__ p, int n) {
  int i = blockIdx.x * blockDim.x + threadIdx.x;
  if (i < n) p[i] = 0;
}

// --- pass 1: fine histogram -------------------------------------------------
__global__ __launch_bounds__(256) void bin_count(const int* __restrict__ dst, int E, int nbins,
                                                 int* __restrict__ binCnt) {
  __shared__ int h[MAX_BINS];
  for (int i = threadIdx.x; i < nbins; i += 256) h[i] = 0;
  __syncthreads();
  int stride = gridDim.x * 256;
  for (int e = blockIdx.x * 256 + threadIdx.x; e < E; e += stride)
    atomicAdd(&h[dst[e] >> BIN_SHIFT], 1);
  __syncthreads();
  for (int i = threadIdx.x; i < nbins; i += 256)
    if (h[i]) atomicAdd(&binCnt[i], h[i]);
}

// --- pass 2: scan fine bins; derive super cursors ---------------------------
__global__ __launch_bounds__(256) void bin_scan(const int* __restrict__ binCnt, int nbins, int E,
                                                int* __restrict__ binStart,
                                                int* __restrict__ binCursor,
                                                int* __restrict__ supCursor) {
  __shared__ int s[256];
  int t = threadIdx.x;
  int c[4];
  int sum = 0;
#pragma unroll
  for (int i = 0; i < 4; i++) {
    int idx = t * 4 + i;
    c[i] = (idx < nbins) ? binCnt[idx] : 0;
    sum += c[i];
  }
  int v = sum;
  s[t] = v;
  __syncthreads();
  for (int d = 1; d < 256; d <<= 1) {
    int add = (t >= d) ? s[t - d] : 0;
    __syncthreads();
    s[t] += add;
    __syncthreads();
  }
  int run = s[t] - v;  // exclusive prefix
#pragma unroll
  for (int i = 0; i < 4; i++) {
    int idx = t * 4 + i;
    if (idx < nbins) {
      binStart[idx] = run;
      binCursor[idx] = run;
      if ((idx & (FINE_PER_SUP - 1)) == 0) supCursor[idx >> 4] = run;  // super segment start
      run += c[i];
    }
  }
  if (t == 0) binStart[nbins] = E;
}

// --- pass 3: partition into super-bins, one 2048-edge tile per block --------
__global__ __launch_bounds__(256) void super_fill(const int* __restrict__ src,
                                                  const int* __restrict__ dst, int E, int nsup,
                                                  int* __restrict__ supCursor,
                                                  unsigned* __restrict__ supbuf) {
  __shared__ unsigned stage[NSUP_MAX * SCAP];
  __shared__ int lcnt[NSUP_MAX], lbase[NSUP_MAX], lscan[NSUP_MAX + 1];
  const int tid = threadIdx.x;
  const int t0 = blockIdx.x * 2048;
  const int t1 = min(E, t0 + 2048);

  int dv[8], sv[8];
#pragma unroll
  for (int i = 0; i < 8; i++) {
    int e = t0 + i * 256 + tid;
    if (e < t1) {
      dv[i] = dst[e];
      sv[i] = src[e];
    }
  }
  if (tid < nsup) lcnt[tid] = 0;
  __syncthreads();
#pragma unroll
  for (int i = 0; i < 8; i++) {
    int e = t0 + i * 256 + tid;
    if (e < t1) {
      int d = dv[i];
      int sb = d >> SUP_SHIFT;
      unsigned v = ((unsigned)(d & ((1 << SUP_SHIFT) - 1)) << SRC_BITS) | (unsigned)sv[i];
      int idx = atomicAdd(&lcnt[sb], 1);
      if (idx < SCAP)
        stage[sb * SCAP + idx] = v;
      else {  // rare overflow: direct write
        int g = atomicAdd(&supCursor[sb], 1);
        supbuf[g] = v;
      }
    }
  }
  __syncthreads();
  if (tid < nsup) {
    int c = min(lcnt[tid], SCAP);
    lcnt[tid] = c;
    lbase[tid] = c ? atomicAdd(&supCursor[tid], c) : 0;
  }
  __syncthreads();
  if (tid < 64) {  // wave-0 inclusive scan over 64 bins
    int vv = (tid < nsup) ? lcnt[tid] : 0;
    int ss = vv;
#pragma unroll
    for (int d = 1; d < 64; d <<= 1) {
      int u = __shfl_up(ss, d);
      if (tid >= d) ss += u;
    }
    lscan[tid + 1] = ss;
    if (tid == 0) lscan[0] = 0;
  }
  __syncthreads();
  int total = lscan[nsup];
  for (int j = tid; j < total; j += 256) {
    int lo = 0, hi = nsup;  // binary search: lscan[lo] <= j < lscan[lo+1]
    while (hi - lo > 1) {
      int mid = (lo + hi) >> 1;
      if (lscan[mid] <= j)
        lo = mid;
      else
        hi = mid;
    }
    int off = j - lscan[lo];
    supbuf[lbase[lo] + off] = stage[lo * SCAP + off];
  }
}

// --- pass 4: scatter super-segment into its 16 fine bins (L2 window) --------
__global__ __launch_bounds__(256) void fine_fill(const unsigned* __restrict__ supbuf,
                                                 const int* __restrict__ binStart, int nbins,
                                                 int* __restrict__ binCursor,
                                                 unsigned* __restrict__ binbuf) {
  __shared__ int lcnt[FINE_PER_SUP], lbase[FINE_PER_SUP];
  int sb = blockIdx.x >> 3, p = blockIdx.x & 7;
  int seg0 = binStart[sb << 4];
  int seg1 = binStart[min((sb + 1) << 4, nbins)];
  int part = (seg1 - seg0 + 7) >> 3;
  int c0 = seg0 + p * part;
  int c1 = min(seg1, c0 + part);
  if (threadIdx.x < FINE_PER_SUP) lcnt[threadIdx.x] = 0;
  __syncthreads();
  for (int i = c0 + threadIdx.x; i < c1; i += 256) atomicAdd(&lcnt[supbuf[i] >> 24], 1);
  __syncthreads();
  if (threadIdx.x < FINE_PER_SUP) {
    int c = lcnt[threadIdx.x];
    lbase[threadIdx.x] = c ? atomicAdd(&binCursor[(sb << 4) + threadIdx.x], c) : 0;
    lcnt[threadIdx.x] = 0;
  }
  __syncthreads();
  for (int i = c0 + threadIdx.x; i < c1; i += 256) {
    unsigned v = supbuf[i];
    unsigned dls = v >> SRC_BITS;  // 11-bit dst-local-to-super
    int f = dls >> BIN_SHIFT;      // fine bin within super
    unsigned vf = ((dls & (BIN_NODES - 1)) << SRC_BITS) | (v & SRC_MASK);
    int idx = lbase[f] + atomicAdd(&lcnt[f], 1);
    binbuf[idx] = vf;
  }
}

// --- pass 5: per-bin node degree + dis --------------------------------------
__global__ __launch_bounds__(256) void node_count_dis(const unsigned* __restrict__ binbuf,
                                                      const int* __restrict__ binStart, int N,
                                                      int* __restrict__ count,
                                                      float* __restrict__ dis) {
  __shared__ int cnt[BIN_NODES];
  int b = blockIdx.x;
  int nodeBase = b << BIN_SHIFT;
  if (threadIdx.x < BIN_NODES) cnt[threadIdx.x] = 0;
  __syncthreads();
  int s0 = binStart[b], s1 = binStart[b + 1];
  for (int i = s0 + threadIdx.x; i < s1; i += 256) atomicAdd(&cnt[binbuf[i] >> SRC_BITS], 1);
  __syncthreads();
  if (threadIdx.x < BIN_NODES) {
    int node = nodeBase + threadIdx.x;
    if (node < N) {
      int c = cnt[threadIdx.x];
      count[node] = c;
      dis[node] = rsqrtf((float)(c + 1));  // +1 self loop
    }
  }
}

// --- pass 6: fused per-bin scan + CSR col scatter ---------------------------
__global__ __launch_bounds__(256) void bin_csr(const unsigned* __restrict__ binbuf,
                                               const int* __restrict__ binStart,
                                               const int* __restrict__ count, int N, int E,
                                               int* __restrict__ rowptr, int* __restrict__ col) {
  __shared__ int cur[BIN_NODES];
  __shared__ int pref[BIN_NODES];
  int b = blockIdx.x, t = threadIdx.x;
  int nodeBase = b << BIN_SHIFT;
  int c = 0;
  if (t < BIN_NODES) {
    int node = nodeBase + t;
    c = (node < N) ? count[node] : 0;
    pref[t] = c;
  }
  __syncthreads();
  for (int d = 1; d < BIN_NODES; d <<= 1) {  // inclusive scan over 128
    int add = (t < BIN_NODES && t >= d) ? pref[t - d] : 0;
    __syncthreads();
    if (t < BIN_NODES) pref[t] += add;
    __syncthreads();
  }
  int s0 = binStart[b];
  if (t < BIN_NODES) {
    int node = nodeBase + t;
    if (node < N) {
      int ex = s0 + pref[t] - c;  // exclusive prefix + segment base
      rowptr[node] = ex;
      cur[t] = ex;
    }
  }
  if (b == 0 && t == 255) rowptr[N] = E;
  __syncthreads();
  int s1 = binStart[b + 1];
  for (int i = s0 + t; i < s1; i += 256) {
    unsigned v = binbuf[i];
    int slot = atomicAdd(&cur[v >> SRC_BITS], 1);
    col[slot] = v & SRC_MASK;
  }
}

// --- pass 7: split W1/W2 into transposed bf16 hi/lo planes ------------------
__global__ __launch_bounds__(256) void wsplit(const float* __restrict__ W1,
                                              const float* __restrict__ W2,
                                              ushort_t* __restrict__ wt1,
                                              ushort_t* __restrict__ wt2) {
  int i = blockIdx.x * 256 + threadIdx.x;
  const float* W;
  ushort_t* wt;
  int K, idx;
  if (i < 256 * 64) {
    W = W1; wt = wt1; K = 256; idx = i;
  } else if (i < 256 * 64 + 64 * 64) {
    W = W2; wt = wt2; K = 64; idx = i - 256 * 64;
  } else
    return;
  int n = idx & 63, k = idx >> 6;
  float f = W[k * 64 + n];  // W is [K][64] row-major
  unsigned u = __float_as_uint(f);
  unsigned hb = u & 0xFFFF0000u;
  float lo = f - __uint_as_float(hb);
  wt[(size_t)n * K + k] = (ushort_t)(u >> 16);
  wt[(size_t)64 * K + (size_t)n * K + k] = (ushort_t)(__float_as_uint(lo) >> 16);
}

// split 8 packed fp32 (as 2 uint4) into bf16 hi (truncate) + lo (trunc resid)
__device__ __forceinline__ void split8u(uint4 a, uint4 b, uint4& xh, uint4& xl) {
  unsigned ua[8] = {a.x, a.y, a.z, a.w, b.x, b.y, b.z, b.w};
  unsigned hw[4], lw[4];
#pragma unroll
  for (int p = 0; p < 4; p++) {
    unsigned u0 = ua[2 * p], u1 = ua[2 * p + 1];
    unsigned h0 = u0 & 0xFFFF0000u, h1 = u1 & 0xFFFF0000u;
    float l0 = __uint_as_float(u0) - __uint_as_float(h0);
    float l1 = __uint_as_float(u1) - __uint_as_float(h1);
    hw[p] = (u0 >> 16) | h1;
    lw[p] = (__float_as_uint(l0) >> 16) | (__float_as_uint(l1) & 0xFFFF0000u);
  }
  xh = make_uint4(hw[0], hw[1], hw[2], hw[3]);
  xl = make_uint4(lw[0], lw[1], lw[2], lw[3]);
}

// --- gemm1: Cbf16[M][64] = x[M][256] @ W1, per-wave LDS-DMA ring ------------
// Each wave owns 32 nodes; per 32-wide k-tile it DMAs its 32 rows (4 KB) into
// its slice of a 3-buffer LDS ring via global_load_lds (4 calls x 1 KB) --
// zero VGPR cost.  Weight loads are issued BEFORE the DMA wait so their L2
// latency overlaps it.  Wait ledger: entering iter j, queue = [st(j):4,
// st(j+1):4 (j<7)]; +weights:8 -> vmcnt(12) drains exactly st(j) (j=7:
// [st(7):4]+w:8 -> vmcnt(8)).  Compiler MFMA-wait = vmcnt(4) keeps st(j+2).
// No __syncthreads.
__global__ __launch_bounds__(256, 3) void gemm1_mfma(const float* __restrict__ A,
                                                     const ushort_t* __restrict__ Wt,
                                                     uint2* __restrict__ Cb, int M) {
  constexpr int K = 256;
  __shared__ uint4 xtile[3][4][256];  // [ring buf][wave][slot] = 48 KB
  const int lane = threadIdx.x & 63;
  const int wv = threadIdx.x >> 6;
  const int l15 = lane & 15;
  const int lq = lane >> 4;
  const int m0 = blockIdx.x * 128 + wv * 32;

  const ushort_t* __restrict__ Wlo = Wt + (size_t)64 * K;

  f32x4 acc[2][4];
#pragma unroll
  for (int a = 0; a < 2; a++)
#pragma unroll
    for (int b = 0; b < 4; b++) acc[a][b] = (f32x4){0.f, 0.f, 0.f, 0.f};

  // stage tile kt into ring buffer buf (this wave's 32 rows, 4 KB, 4 DMA calls)
  auto stage_tile = [&](int kt, int buf) {
#pragma unroll
    for (int c = 0; c < 4; c++) {
      int s = c * 64 + lane;
      int r = s >> 3;                 // row 0..31 within wave block
      int c4 = (s & 7) ^ (r & 7);     // swizzled float4-column
      int nd = m0 + r;
      if (nd >= M) nd = M - 1;
      const float* gp = A + (size_t)nd * K + kt * 32 + c4 * 4;
      __builtin_amdgcn_global_load_lds(
          (const __attribute__((address_space(1))) void*)gp,
          (__attribute__((address_space(3))) void*)&xtile[buf][wv][c * 64], 16, 0, 0);
    }
  };

  // prologue: st(0), st(1)
  stage_tile(0, 0);
  stage_tile(1, 1);
  __builtin_amdgcn_sched_barrier(0);

#pragma unroll
  for (int j = 0; j < 8; j++) {
    // a. issue this iteration's weight loads FIRST -- their L2 latency
    //    overlaps the st(j) DMA wait below
    FragB w[8];
    {
      const int kb = j * 32 + lq * 8;
#pragma unroll
      for (int nt = 0; nt < 4; nt++) {
        w[nt].u = *(const uint4*)(Wt + (size_t)(nt * 16 + l15) * K + kb);
        w[4 + nt].u = *(const uint4*)(Wlo + (size_t)(nt * 16 + l15) * K + kb);
      }
    }
    __builtin_amdgcn_sched_barrier(0);
    // b. ensure tile j staged: queue=[st(j):4, st(j+1):4 (j<7), w:8]
    if (j < 7)
      asm volatile("s_waitcnt vmcnt(12)" ::: "memory");
    else
      asm volatile("s_waitcnt vmcnt(8)" ::: "memory");
    __builtin_amdgcn_sched_barrier(0);
    // c. ds_read tile j fragments (swizzled)
    uint4 xa[2][2];
#pragma unroll
    for (int mt = 0; mt < 2; mt++) {
      int mr = mt * 16 + l15;
#pragma unroll
      for (int hh = 0; hh < 2; hh++) {
        int c4 = (lq * 2 + hh) ^ (mr & 7);
        xa[mt][hh] = *(const uint4*)&xtile[j % 3][wv][mr * 8 + c4];
      }
    }
    __builtin_amdgcn_sched_barrier(0);
    // d. issue stage for tile j+2
    if (j + 2 < 8) stage_tile(j + 2, (j + 2) % 3);
    __builtin_amdgcn_sched_barrier(0);
    // e. split + MFMA (compiler weight-wait = vmcnt(4), keeps st(j+2) alive)
    FragB xh0, xl0, xh1, xl1;
    split8u(xa[0][0], xa[0][1], xh0.u, xl0.u);
    split8u(xa[1][0], xa[1][1], xh1.u, xl1.u);
#pragma unroll
    for (int nt = 0; nt < 4; nt++) {
      acc[0][nt] = __builtin_amdgcn_mfma_f32_16x16x32_bf16(w[nt].b, xh0.b, acc[0][nt], 0, 0, 0);
      acc[0][nt] = __builtin_amdgcn_mfma_f32_16x16x32_bf16(w[nt].b, xl0.b, acc[0][nt], 0, 0, 0);
      acc[1][nt] = __builtin_amdgcn_mfma_f32_16x16x32_bf16(w[nt].b, xh1.b, acc[1][nt], 0, 0, 0);
      acc[1][nt] = __builtin_amdgcn_mfma_f32_16x16x32_bf16(w[nt].b, xl1.b, acc[1][nt], 0, 0, 0);
    }
#pragma unroll
    for (int nt = 0; nt < 4; nt++) {
      acc[0][nt] = __builtin_amdgcn_mfma_f32_16x16x32_bf16(w[4 + nt].b, xh0.b, acc[0][nt], 0, 0, 0);
      acc[1][nt] = __builtin_amdgcn_mfma_f32_16x16x32_bf16(w[4 + nt].b, xh1.b, acc[1][nt], 0, 0, 0);
    }
  }

#pragma unroll
  for (int mt = 0; mt < 2; mt++) {
    int node = m0 + mt * 16 + l15;
    if (node < M) {
      uint2* cp = Cb + (size_t)node * 16 + lq;
#pragma unroll
      for (int nt = 0; nt < 4; nt++) {
        float4 o = make_float4(acc[mt][nt][0], acc[mt][nt][1], acc[mt][nt][2], acc[mt][nt][3]);
        cp[nt * 4] = f42bfq(o);  // cols nt*16 + lq*4 .. +3
      }
    }
  }
}

// --- gemm2: Cbf16[M][64] = out1[M][64] @ W2 (A exact bf16, 2-term) ----------
__global__ __launch_bounds__(256, 3) void gemm2_mfma(const ushort_t* __restrict__ Av,
                                                     const ushort_t* __restrict__ Wt,
                                                     uint2* __restrict__ Cb, int M) {
  constexpr int K = 64;
  constexpr int NT = K / 32;  // 2
  const int lane = threadIdx.x & 63;
  const int wv = threadIdx.x >> 6;
  const int l15 = lane & 15;
  const int lq = lane >> 4;
  const int m0 = blockIdx.x * 128 + wv * 32;

  const ushort_t* __restrict__ Wlo = Wt + (size_t)64 * K;

  f32x4 acc[2][4];
#pragma unroll
  for (int a = 0; a < 2; a++)
#pragma unroll
    for (int b = 0; b < 4; b++) acc[a][b] = (f32x4){0.f, 0.f, 0.f, 0.f};

  int node[2], ncl[2];
#pragma unroll
  for (int mt = 0; mt < 2; mt++) {
    node[mt] = m0 + mt * 16 + l15;
    ncl[mt] = node[mt] < M ? node[mt] : (M - 1);
  }

  FragB xa[NT][2], wh[NT][4], wl[NT][4];
#pragma unroll
  for (int t = 0; t < NT; t++)
#pragma unroll
    for (int mt = 0; mt < 2; mt++)
      xa[t][mt].u = *(const uint4*)(Av + (size_t)ncl[mt] * K + t * 32 + lq * 8);
#pragma unroll
  for (int t = 0; t < NT; t++)
#pragma unroll
    for (int nt = 0; nt < 4; nt++) {
      wh[t][nt].u = *(const uint4*)(Wt + (size_t)(nt * 16 + l15) * K + t * 32 + lq * 8);
      wl[t][nt].u = *(const uint4*)(Wlo + (size_t)(nt * 16 + l15) * K + t * 32 + lq * 8);
    }
#pragma unroll
  for (int t = 0; t < NT; t++)
#pragma unroll
    for (int mt = 0; mt < 2; mt++)
#pragma unroll
      for (int nt = 0; nt < 4; nt++) {
        acc[mt][nt] =
            __builtin_amdgcn_mfma_f32_16x16x32_bf16(wh[t][nt].b, xa[t][mt].b, acc[mt][nt], 0, 0, 0);
        acc[mt][nt] =
            __builtin_amdgcn_mfma_f32_16x16x32_bf16(wl[t][nt].b, xa[t][mt].b, acc[mt][nt], 0, 0, 0);
      }

#pragma unroll
  for (int mt = 0; mt < 2; mt++) {
    if (node[mt] < M) {
      uint2* cp = Cb + (size_t)node[mt] * 16 + lq;
#pragma unroll
      for (int nt = 0; nt < 4; nt++) {
        float4 o = make_float4(acc[mt][nt][0], acc[mt][nt][1], acc[mt][nt][2], acc[mt][nt][3]);
        cp[nt * 4] = f42bfq(o);
      }
    }
  }
}

// --- aggregation: wave per node, depth-4 rolling gather pipeline ------------
// w_edge = dis[src]; final sum scaled by di = dis[dst] once:
//   out = di * ( sum_j dis[src_j]*h_j + di*h_self ) + bias
// 4 gather slots (g0..g3) kept in flight; consume-oldest then reissue gives
// ~4x128B outstanding per wave (r5 structure had ~2 -> 2.2 TB/s measured;
// this targets ~2x).  rounds is wave-uniform so all guards are uniform.
template <bool OUTBF>
__global__ __launch_bounds__(256) void agg_kernel(
    const uint2* __restrict__ h, const int* __restrict__ rowptr, const int* __restrict__ col,
    const float* __restrict__ dis, const float* __restrict__ bias, void* __restrict__ outv,
    int N, int relu) {
  int wid = (blockIdx.x * blockDim.x + threadIdx.x) >> 6;
  if (wid >= N) return;
  int lane = threadIdx.x & 63;
  int sub = lane & 15;
  int quarter = lane >> 4;

  int start = rowptr[wid], end = rowptr[wid + 1];
  float di = dis[wid];

  float4 a0 = make_float4(0.f, 0.f, 0.f, 0.f), a1 = a0, a2 = a0, a3 = a0;
  {  // self-loop: di*h_self (quarter 0 only); final *di makes it di^2
    float4 self = bfq2f4(h[(size_t)wid * 16 + sub]);
    if (quarter == 0) {
      a0.x = di * self.x;
      a0.y = di * self.y;
      a0.z = di * self.z;
      a0.w = di * self.w;
    }
  }

  for (int base = start; base < end; base += 64) {
    int e = base + lane;
    int sj = 0;
    float wj = 0.f;
    if (e < end) {
      sj = col[e];
      wj = dis[sj];  // L2-resident 400 KB table
    }
    int cnt = end - base;
    if (cnt > 64) cnt = 64;
    int rounds = (cnt + 3) >> 2;  // wave-uniform

    uint2 g0, g1, g2, g3;
    float w0, w1, w2, w3;
// issue group gi (edges 4*gi+quarter); uniform guard gi<rounds
#define ISSUE(gi, G, W)                                              \
  do {                                                               \
    int _i = (4 * (gi) + quarter) & 63;                              \
    int _s = __shfl(sj, _i);                                         \
    float _w = __shfl(wj, _i);                                       \
    if ((gi) < rounds) {                                             \
      G = h[(size_t)_s * 16 + sub];                                  \
      W = _w;                                                        \
    } else {                                                         \
      G = make_uint2(0u, 0u);                                        \
      W = 0.f;                                                       \
    }                                                                \
  } while (0)

    ISSUE(0, g0, w0);
    ISSUE(1, g1, w1);
    ISSUE(2, g2, w2);
    ISSUE(3, g3, w3);
    int rounds4 = (rounds + 3) & ~3;
    for (int t0 = 0; t0 < rounds4; t0 += 4) {
      {
        float4 gf = bfq2f4(g0);
        a0.x += w0 * gf.x; a0.y += w0 * gf.y; a0.z += w0 * gf.z; a0.w += w0 * gf.w;
      }
      ISSUE(t0 + 4, g0, w0);
      {
        float4 gf = bfq2f4(g1);
        a1.x += w1 * gf.x; a1.y += w1 * gf.y; a1.z += w1 * gf.z; a1.w += w1 * gf.w;
      }
      ISSUE(t0 + 5, g1, w1);
      {
        float4 gf = bfq2f4(g2);
        a2.x += w2 * gf.x; a2.y += w2 * gf.y; a2.z += w2 * gf.z; a2.w += w2 * gf.w;
      }
      ISSUE(t0 + 6, g2, w2);
      {
        float4 gf = bfq2f4(g3);
        a3.x += w3 * gf.x; a3.y += w3 * gf.y; a3.z += w3 * gf.z; a3.w += w3 * gf.w;
      }
      ISSUE(t0 + 7, g3, w3);
    }
#undef ISSUE
  }

  float sx = (a0.x + a1.x) + (a2.x + a3.x);
  float sy = (a0.y + a1.y) + (a2.y + a3.y);
  float sz = (a0.z + a1.z) + (a2.z + a3.z);
  float sw = (a0.w + a1.w) + (a2.w + a3.w);
  sx += __shfl_down(sx, 32); sy += __shfl_down(sy, 32);
  sz += __shfl_down(sz, 32); sw += __shfl_down(sw, 32);
  sx += __shfl_down(sx, 16); sy += __shfl_down(sy, 16);
  sz += __shfl_down(sz, 16); sw += __shfl_down(sw, 16);
  if (quarter == 0) {
    float4 bv = ((const float4*)bias)[sub];
    float4 o = make_float4(di * sx + bv.x, di * sy + bv.y, di * sz + bv.z, di * sw + bv.w);
    if (relu) {
      o.x = fmaxf(o.x, 0.f);
      o.y = fmaxf(o.y, 0.f);
      o.z = fmaxf(o.z, 0.f);
      o.w = fmaxf(o.w, 0.f);
    }
    if (OUTBF)
      ((uint2*)outv)[(size_t)wid * 16 + sub] = f42bfq(o);
    else
      ((float4*)outv)[(size_t)wid * 16 + sub] = o;
  }
}

// ---------------------------------------------------------------------------
extern "C" void kernel_launch(void* const* d_in, const int* in_sizes, int n_in,
                              void* d_out, int out_size, void* d_ws, size_t ws_size,
                              hipStream_t stream) {
  const float* x = (const float*)d_in[0];
  const int* ei = (const int*)d_in[1];
  const float* W1 = (const float*)d_in[2];
  const float* b1 = (const float*)d_in[3];
  const float* W2 = (const float*)d_in[4];
  const float* b2 = (const float*)d_in[5];

  const int IN = 256;
  const int E = in_sizes[1] / 2;
  const int N = in_sizes[0] / IN;
  const int* src = ei;
  const int* dst = ei + E;
  const int nbins = (N + BIN_NODES - 1) >> BIN_SHIFT;
  const int nsup = (N + (1 << SUP_SHIFT) - 1) >> SUP_SHIFT;

  // workspace carve-up (256B aligned)
  char* ws = (char*)d_ws;
  size_t off = 0;
  auto alloc = [&](size_t bytes) -> void* {
    void* p = ws + off;
    off += (bytes + 255) & ~(size_t)255;
    return p;
  };
  int* count = (int*)alloc((size_t)N * 4);
  int* rowptr = (int*)alloc((size_t)(N + 1) * 4);
  float* dis = (float*)alloc((size_t)N * 4);
  int* binCnt = (int*)alloc(MAX_BINS * 4);
  int* binStart = (int*)alloc((MAX_BINS + 1) * 4);
  int* binCursor = (int*)alloc(MAX_BINS * 4);
  int* supCursor = (int*)alloc(NSUP_MAX * 4);
  int* col = (int*)alloc((size_t)E * 4);                // 12.8 MB; written by bin_csr
  unsigned* supbuf = (unsigned*)col;                    // alias: dead before col written
  uint2* out1 = (uint2*)alloc((size_t)N * 64 * 2);      // bf16 layer-1 activations
  size_t big = ((size_t)E * 4 > (size_t)N * 128) ? (size_t)E * 4 : (size_t)N * 128;
  unsigned* binbuf = (unsigned*)alloc(big);             // aliases h (dead before gemm1)
  uint2* h = (uint2*)binbuf;
  ushort_t* wt1 = (ushort_t*)alloc((size_t)2 * 64 * 256 * 2);  // 64 KB split W1
  ushort_t* wt2 = (ushort_t*)alloc((size_t)2 * 64 * 64 * 2);   // 16 KB split W2
  float* outf = (float*)d_out;

  zero_int<<<(nbins + 255) / 256, 256, 0, stream>>>(binCnt, nbins);
  bin_count<<<1024, 256, 0, stream>>>(dst, E, nbins, binCnt);
  bin_scan<<<1, 256, 0, stream>>>(binCnt, nbins, E, binStart, binCursor, supCursor);
  super_fill<<<(E + 2047) / 2048, 256, 0, stream>>>(src, dst, E, nsup, supCursor, supbuf);
  fine_fill<<<nsup * 8, 256, 0, stream>>>(supbuf, binStart, nbins, binCursor, binbuf);
  node_count_dis<<<nbins, 256, 0, stream>>>(binbuf, binStart, N, count, dis);
  bin_csr<<<nbins, 256, 0, stream>>>(binbuf, binStart, count, N, E, rowptr, col);
  wsplit<<<(256 * 64 + 64 * 64 + 255) / 256, 256, 0, stream>>>(W1, W2, wt1, wt2);

  gemm1_mfma<<<(N + 127) / 128, 256, 0, stream>>>(x, wt1, h, N);
  agg_kernel<true><<<(N + 3) / 4, 256, 0, stream>>>(h, rowptr, col, dis, b1, out1, N, 1);
  gemm2_mfma<<<(N + 127) / 128, 256, 0, stream>>>((const ushort_t*)out1, wt2, h, N);
  agg_kernel<false><<<(N + 3) / 4, 256, 0, stream>>>(h, rowptr, col, dis, b2, outf, N, 0);
}